// Round 3
// baseline (1338.726 us; speedup 1.0000x reference)
//
#include <hip/hip_runtime.h>
#include <hip/hip_bf16.h>
#include <math.h>

#define NN 100000
#define NE 1600000

// bf16 <-> f32 helpers (bf16 stored as raw ushort; value<<16 == f32 bits)
__device__ __forceinline__ float bf2f(unsigned short u) {
    union { unsigned int u; float f; } c; c.u = ((unsigned int)u) << 16; return c.f;
}
__device__ __forceinline__ unsigned short f2bf(float f) {
    union { float f; unsigned int u; } c; c.f = f;
    unsigned int x = c.u;
    return (unsigned short)((x + 0x7fffu + ((x >> 16) & 1u)) >> 16); // RNE
}

typedef __attribute__((ext_vector_type(8))) short short8;
typedef __attribute__((ext_vector_type(4))) float float4v;

// ---------------- CSR build ----------------

__global__ void k_zero(int* __restrict__ p, int n) {
    int i = blockIdx.x * blockDim.x + threadIdx.x;
    if (i < n) p[i] = 0;
}

__global__ void k_count(const int* __restrict__ dst, int* __restrict__ cnt) {
    int e = blockIdx.x * blockDim.x + threadIdx.x;
    if (e < NE) {
        int d = dst[e];
        if ((unsigned)d < (unsigned)NN) atomicAdd(&cnt[d], 1);
    }
}

__global__ void k_dinv(const int* __restrict__ cnt, float* __restrict__ dinv) {
    int i = blockIdx.x * blockDim.x + threadIdx.x;
    if (i < NN) dinv[i] = rsqrtf((float)max(cnt[i] + 1, 1));  // +1 = self loop
}

// single-block exclusive scan, 1024 threads x 8 elems/iter
__global__ void k_scan(const int* __restrict__ cnt, int* __restrict__ off) {
    __shared__ int s[1024];
    __shared__ int carry_s;
    int t = threadIdx.x;
    if (t == 0) carry_s = 0;
    __syncthreads();
    for (int base = 0; base < NN; base += 8192) {
        int i0 = base + t * 8;
        int v[8]; int tot = 0;
#pragma unroll
        for (int j = 0; j < 8; ++j) { int i = i0 + j; v[j] = (i < NN) ? cnt[i] : 0; tot += v[j]; }
        s[t] = tot;
        __syncthreads();
        for (int d = 1; d < 1024; d <<= 1) {
            int x = (t >= d) ? s[t - d] : 0;
            __syncthreads();
            s[t] += x;
            __syncthreads();
        }
        int incl = s[t];
        int carry = carry_s;
        int run = carry + incl - tot;
#pragma unroll
        for (int j = 0; j < 8; ++j) { int i = i0 + j; if (i < NN) off[i] = run; run += v[j]; }
        __syncthreads();
        if (t == 1023) carry_s = carry + incl;
        __syncthreads();
    }
    if (t == 0) off[NN] = carry_s;
}

// cursor aliases cnt (re-zeroed after scan)
__global__ void k_fill(const int* __restrict__ ei, const int* __restrict__ off,
                       int* __restrict__ cursor, int* __restrict__ csr) {
    int e = blockIdx.x * blockDim.x + threadIdx.x;
    if (e >= NE) return;
    int s = ei[e];
    int d = ei[NE + e];
    if ((unsigned)d >= (unsigned)NN) return;
    int pos = off[d] + atomicAdd(&cursor[d], 1);
    if ((unsigned)pos < (unsigned)NE) csr[pos] = s;
}

// ---------------- weight transpose + f32->bf16 downcast (tiny) ----------------
__global__ void k_w1t(const float* __restrict__ W, unsigned short* __restrict__ Wt) {
    int idx = blockIdx.x * 256 + threadIdx.x;   // 16384
    int n = idx >> 7, k = idx & 127;
    Wt[n * 128 + k] = f2bf(W[k * 128 + n]);     // W1 is [IN=128][HID=128]
}
__global__ void k_w2t(const float* __restrict__ Wmu, const float* __restrict__ Wls,
                      unsigned short* __restrict__ Wt) {
    int idx = blockIdx.x * 256 + threadIdx.x;   // 16384
    int n = idx >> 7, k = idx & 127;            // Wmu/Wls are [HID=128][OUT=64]
    float v = (n < 64) ? Wmu[k * 64 + n] : Wls[k * 64 + (n - 64)];
    Wt[n * 128 + k] = f2bf(v);
}

// ---------------- fused 1: h = (A_norm @ x) @ W1 + b1 ----------------
// gather f32 x rows -> f32 accumulate -> bf16 As; MFMA; h stored bf16.
// block: 256 thr (4 waves), 64 rows x 128 cols, K=128.
__global__ __launch_bounds__(256) void k_fused1(
    const float* __restrict__ xin,           // [NN][128] f32
    const int* __restrict__ off, const int* __restrict__ csr,
    const float* __restrict__ dinv,
    const unsigned short* __restrict__ Bt,   // [128][128] bf16 W1t (n-major, k-contig)
    const float* __restrict__ bias,          // [128] f32
    unsigned short* __restrict__ Cg,         // h [NN][128] bf16
    int nrows) {
    __shared__ __align__(16) unsigned short As[64 * 136];
    __shared__ __align__(16) unsigned short Bs[128 * 136];
    int tid = threadIdx.x;
    int lane = tid & 63, wave = tid >> 6;
    int r0 = blockIdx.x * 64;
    for (int c = tid; c < 2048; c += 256) {
        int nr = c >> 4, kc = (c & 15) << 3;
        *(short8*)(Bs + nr * 136 + kc) = *(const short8*)(Bt + nr * 128 + kc);
    }
    // gather: lane handles feats {2*lane, 2*lane+1}; wave handles 16 consecutive rows
    for (int i = 0; i < 16; ++i) {
        int row = wave * 16 + i;
        int node = r0 + row;
        unsigned int stv = 0;
        if (node < nrows) {
            float di = dinv[node];
            float2 p = *(const float2*)(xin + (size_t)node * 128 + lane * 2);
            float accx = di * p.x, accy = di * p.y;
            int b = off[node], e = off[node + 1];
            for (int t = b; t < e; ++t) {
                int s = csr[t];
                if ((unsigned)s >= (unsigned)NN) continue;
                float ds = dinv[s];
                float2 q = *(const float2*)(xin + (size_t)s * 128 + lane * 2);
                accx += ds * q.x;
                accy += ds * q.y;
            }
            stv = ((unsigned int)f2bf(accy * di) << 16) | (unsigned int)f2bf(accx * di);
        }
        *(unsigned int*)(As + row * 136 + lane * 2) = stv;
    }
    __syncthreads();
    int quad = lane >> 4, l16 = lane & 15;
    int colbase = wave * 32;
    short8 bfr[4][2];
#pragma unroll
    for (int ks = 0; ks < 4; ++ks)
#pragma unroll
        for (int ct = 0; ct < 2; ++ct)
            bfr[ks][ct] = *(const short8*)(Bs + (colbase + ct * 16 + l16) * 136 + ks * 32 + quad * 8);
    float4v acc[4][2];
#pragma unroll
    for (int rt = 0; rt < 4; ++rt)
#pragma unroll
        for (int ct = 0; ct < 2; ++ct) { float4v z = {0.f, 0.f, 0.f, 0.f}; acc[rt][ct] = z; }
#pragma unroll
    for (int ks = 0; ks < 4; ++ks) {
        short8 af[4];
#pragma unroll
        for (int rt = 0; rt < 4; ++rt)
            af[rt] = *(const short8*)(As + (rt * 16 + l16) * 136 + ks * 32 + quad * 8);
#pragma unroll
        for (int rt = 0; rt < 4; ++rt)
#pragma unroll
            for (int ct = 0; ct < 2; ++ct)
                acc[rt][ct] = __builtin_amdgcn_mfma_f32_16x16x32_bf16(af[rt], bfr[ks][ct], acc[rt][ct], 0, 0, 0);
    }
    float bcol[2];
#pragma unroll
    for (int ct = 0; ct < 2; ++ct) bcol[ct] = bias[colbase + ct * 16 + l16];
#pragma unroll
    for (int rt = 0; rt < 4; ++rt)
#pragma unroll
        for (int reg = 0; reg < 4; ++reg) {
            int gr = r0 + rt * 16 + quad * 4 + reg;
            if (gr < nrows) {
#pragma unroll
                for (int ct = 0; ct < 2; ++ct)
                    Cg[(size_t)gr * 128 + colbase + ct * 16 + l16] = f2bf(acc[rt][ct][reg] + bcol[ct]);
            }
        }
}

// ---------- fused 2: [mu|ls] = (A_norm @ h) @ W2t + [bmu|bls]; out = mu + init*exp(ls) ----------
__global__ __launch_bounds__(256) void k_fused2(
    const unsigned short* __restrict__ hin,  // [NN][128] bf16
    const int* __restrict__ off, const int* __restrict__ csr,
    const float* __restrict__ dinv,
    const unsigned short* __restrict__ Bt,   // [128][128] bf16 W2t
    const float* __restrict__ bmu,           // [64] f32
    const float* __restrict__ bls,           // [64] f32
    const float* __restrict__ init,          // [NN][64] f32
    float* __restrict__ outp,                // [NN][64] f32
    int nrows) {
    __shared__ __align__(16) unsigned short As[64 * 136];
    __shared__ __align__(16) unsigned short Bs[128 * 136];  // reused as Cs (f32 64x128 = 32KB)
    int tid = threadIdx.x;
    int lane = tid & 63, wave = tid >> 6;
    int r0 = blockIdx.x * 64;
    for (int c = tid; c < 2048; c += 256) {
        int nr = c >> 4, kc = (c & 15) << 3;
        *(short8*)(Bs + nr * 136 + kc) = *(const short8*)(Bt + nr * 128 + kc);
    }
    for (int i = 0; i < 16; ++i) {
        int row = wave * 16 + i;
        int node = r0 + row;
        unsigned int stv = 0;
        if (node < nrows) {
            float di = dinv[node];
            unsigned int p = *(const unsigned int*)(hin + (size_t)node * 128 + lane * 2);
            float accx = di * bf2f((unsigned short)(p & 0xffffu));
            float accy = di * bf2f((unsigned short)(p >> 16));
            int b = off[node], e = off[node + 1];
            for (int t = b; t < e; ++t) {
                int s = csr[t];
                if ((unsigned)s >= (unsigned)NN) continue;
                float ds = dinv[s];
                unsigned int q = *(const unsigned int*)(hin + (size_t)s * 128 + lane * 2);
                accx += ds * bf2f((unsigned short)(q & 0xffffu));
                accy += ds * bf2f((unsigned short)(q >> 16));
            }
            stv = ((unsigned int)f2bf(accy * di) << 16) | (unsigned int)f2bf(accx * di);
        }
        *(unsigned int*)(As + row * 136 + lane * 2) = stv;
    }
    __syncthreads();
    int quad = lane >> 4, l16 = lane & 15;
    int colbase = wave * 32;
    short8 bfr[4][2];
#pragma unroll
    for (int ks = 0; ks < 4; ++ks)
#pragma unroll
        for (int ct = 0; ct < 2; ++ct)
            bfr[ks][ct] = *(const short8*)(Bs + (colbase + ct * 16 + l16) * 136 + ks * 32 + quad * 8);
    float4v acc[4][2];
#pragma unroll
    for (int rt = 0; rt < 4; ++rt)
#pragma unroll
        for (int ct = 0; ct < 2; ++ct) { float4v z = {0.f, 0.f, 0.f, 0.f}; acc[rt][ct] = z; }
#pragma unroll
    for (int ks = 0; ks < 4; ++ks) {
        short8 af[4];
#pragma unroll
        for (int rt = 0; rt < 4; ++rt)
            af[rt] = *(const short8*)(As + (rt * 16 + l16) * 136 + ks * 32 + quad * 8);
#pragma unroll
        for (int rt = 0; rt < 4; ++rt)
#pragma unroll
            for (int ct = 0; ct < 2; ++ct)
                acc[rt][ct] = __builtin_amdgcn_mfma_f32_16x16x32_bf16(af[rt], bfr[ks][ct], acc[rt][ct], 0, 0, 0);
    }
    float bcol[2];
#pragma unroll
    for (int ct = 0; ct < 2; ++ct) {
        int col = colbase + ct * 16 + l16;
        bcol[ct] = (col < 64) ? bmu[col] : bls[col - 64];
    }
    __syncthreads();  // all waves done reading Bs/As (frags in registers)
    float* Cs = (float*)Bs;
#pragma unroll
    for (int rt = 0; rt < 4; ++rt)
#pragma unroll
        for (int reg = 0; reg < 4; ++reg) {
            int lr = rt * 16 + quad * 4 + reg;
#pragma unroll
            for (int ct = 0; ct < 2; ++ct)
                Cs[lr * 128 + colbase + ct * 16 + l16] = acc[rt][ct][reg] + bcol[ct];
        }
    __syncthreads();
    for (int c = tid; c < 4096; c += 256) {
        int row = c >> 6, j = c & 63;
        int gr = r0 + row;
        if (gr < nrows) {
            float mu = Cs[row * 128 + j];
            float ls = Cs[row * 128 + 64 + j];
            float idv = init[(size_t)gr * 64 + j];
            outp[(size_t)gr * 64 + j] = mu + idv * expf(ls);
        }
    }
}

extern "C" void kernel_launch(void* const* d_in, const int* in_sizes, int n_in,
                              void* d_out, int out_size, void* d_ws, size_t ws_size,
                              hipStream_t stream) {
    const float* x   = (const float*)d_in[0];  // [N,128] f32
    const int*   ei  = (const int*)d_in[1];    // [2,E] int32
    const float* ind = (const float*)d_in[2];  // [N,64] f32
    const float* W1  = (const float*)d_in[3];  // [128,128] f32
    const float* b1  = (const float*)d_in[4];  // [128] f32
    const float* Wmu = (const float*)d_in[5];  // [128,64] f32
    const float* bmu = (const float*)d_in[6];  // [64] f32
    const float* Wls = (const float*)d_in[7];  // [128,64] f32
    const float* bls = (const float*)d_in[8];  // [64] f32
    float* outp = (float*)d_out;               // [N,64] f32

    char* w = (char*)d_ws;
    auto carve = [&](size_t bytes) -> char* {
        char* p = w; w += (bytes + 255) & ~(size_t)255; return p;
    };
    int*   cnt  = (int*)carve((size_t)NN * 4);        // doubles as cursor after scan
    int*   off  = (int*)carve((size_t)(NN + 1) * 4);
    float* dinv = (float*)carve((size_t)NN * 4);
    int*   csr  = (int*)carve((size_t)NE * 4);
    unsigned short* W1t = (unsigned short*)carve(128 * 128 * 2);
    unsigned short* W2t = (unsigned short*)carve(128 * 128 * 2);
    unsigned short* h   = (unsigned short*)carve((size_t)NN * 128 * 2);
    // total ~33.3 MB of ws

    k_zero<<<391, 256, 0, stream>>>(cnt, NN);
    k_w1t<<<64, 256, 0, stream>>>(W1, W1t);
    k_w2t<<<64, 256, 0, stream>>>(Wmu, Wls, W2t);
    k_count<<<(NE + 255) / 256, 256, 0, stream>>>(ei + NE, cnt);
    k_dinv<<<391, 256, 0, stream>>>(cnt, dinv);
    k_scan<<<1, 1024, 0, stream>>>(cnt, off);
    k_zero<<<391, 256, 0, stream>>>(cnt, NN);  // reuse cnt as fill cursor
    k_fill<<<(NE + 255) / 256, 256, 0, stream>>>(ei, off, cnt, csr);
    k_fused1<<<(NN + 63) / 64, 256, 0, stream>>>(x, off, csr, dinv, W1t, b1, h, NN);
    k_fused2<<<(NN + 63) / 64, 256, 0, stream>>>(h, off, csr, dinv, W2t, bmu, bls, ind, outp, NN);
}

// Round 4
// 627.898 us; speedup vs baseline: 2.1321x; 2.1321x over previous
//
#include <hip/hip_runtime.h>
#include <hip/hip_bf16.h>
#include <math.h>

#define NN 100000
#define NE 1600000

// bf16 <-> f32 helpers (bf16 stored as raw ushort; value<<16 == f32 bits)
__device__ __forceinline__ float bf2f(unsigned short u) {
    union { unsigned int u; float f; } c; c.u = ((unsigned int)u) << 16; return c.f;
}
__device__ __forceinline__ unsigned short f2bf(float f) {
    union { float f; unsigned int u; } c; c.f = f;
    unsigned int x = c.u;
    return (unsigned short)((x + 0x7fffu + ((x >> 16) & 1u)) >> 16); // RNE
}

typedef __attribute__((ext_vector_type(8))) short short8;
typedef __attribute__((ext_vector_type(4))) float float4v;

// ---------------- CSR build ----------------

__global__ void k_zero(int* __restrict__ p, int n) {
    int i = blockIdx.x * blockDim.x + threadIdx.x;
    if (i < n) p[i] = 0;
}

__global__ void k_count(const int* __restrict__ dst, int* __restrict__ cnt) {
    int e = blockIdx.x * blockDim.x + threadIdx.x;
    if (e < NE) {
        int d = dst[e];
        if ((unsigned)d < (unsigned)NN) atomicAdd(&cnt[d], 1);
    }
}

__global__ void k_dinv(const int* __restrict__ cnt, float* __restrict__ dinv) {
    int i = blockIdx.x * blockDim.x + threadIdx.x;
    if (i < NN) dinv[i] = rsqrtf((float)max(cnt[i] + 1, 1));  // +1 = self loop
}

// single-block exclusive scan, 1024 threads x 8 elems/iter
__global__ void k_scan(const int* __restrict__ cnt, int* __restrict__ off) {
    __shared__ int s[1024];
    __shared__ int carry_s;
    int t = threadIdx.x;
    if (t == 0) carry_s = 0;
    __syncthreads();
    for (int base = 0; base < NN; base += 8192) {
        int i0 = base + t * 8;
        int v[8]; int tot = 0;
#pragma unroll
        for (int j = 0; j < 8; ++j) { int i = i0 + j; v[j] = (i < NN) ? cnt[i] : 0; tot += v[j]; }
        s[t] = tot;
        __syncthreads();
        for (int d = 1; d < 1024; d <<= 1) {
            int x = (t >= d) ? s[t - d] : 0;
            __syncthreads();
            s[t] += x;
            __syncthreads();
        }
        int incl = s[t];
        int carry = carry_s;
        int run = carry + incl - tot;
#pragma unroll
        for (int j = 0; j < 8; ++j) { int i = i0 + j; if (i < NN) off[i] = run; run += v[j]; }
        __syncthreads();
        if (t == 1023) carry_s = carry + incl;
        __syncthreads();
    }
    if (t == 0) off[NN] = carry_s;
}

// cursor aliases cnt (re-zeroed after scan)
__global__ void k_fill(const int* __restrict__ ei, const int* __restrict__ off,
                       int* __restrict__ cursor, int* __restrict__ csr) {
    int e = blockIdx.x * blockDim.x + threadIdx.x;
    if (e >= NE) return;
    int s = ei[e];
    int d = ei[NE + e];
    if ((unsigned)d >= (unsigned)NN) return;
    int pos = off[d] + atomicAdd(&cursor[d], 1);
    if ((unsigned)pos < (unsigned)NE) csr[pos] = s;
}

// ---------------- prescale: xs[i][j] = bf16(dinv[i] * x[i][j]) ----------------
__global__ __launch_bounds__(256) void k_prescale(const float* __restrict__ x,
        const float* __restrict__ dinv, unsigned short* __restrict__ xs) {
    int i = blockIdx.x * 256 + threadIdx.x;   // NN*32 threads, 4 feats each
    if (i >= NN * 32) return;
    int node = i >> 5, c = (i & 31) << 2;
    float d = dinv[node];
    float4 v = *(const float4*)(x + (size_t)node * 128 + c);
    uint2 st;
    st.x = ((unsigned int)f2bf(d * v.y) << 16) | f2bf(d * v.x);
    st.y = ((unsigned int)f2bf(d * v.w) << 16) | f2bf(d * v.z);
    *(uint2*)(xs + (size_t)node * 128 + c) = st;
}

// ---------------- weight transpose + f32->bf16 downcast (tiny) ----------------
__global__ void k_w1t(const float* __restrict__ W, unsigned short* __restrict__ Wt) {
    int idx = blockIdx.x * 256 + threadIdx.x;   // 16384
    int n = idx >> 7, k = idx & 127;
    Wt[n * 128 + k] = f2bf(W[k * 128 + n]);     // W1 is [IN=128][HID=128]
}
__global__ void k_w2t(const float* __restrict__ Wmu, const float* __restrict__ Wls,
                      unsigned short* __restrict__ Wt) {
    int idx = blockIdx.x * 256 + threadIdx.x;   // 16384
    int n = idx >> 7, k = idx & 127;            // Wmu/Wls are [HID=128][OUT=64]
    float v = (n < 64) ? Wmu[k * 64 + n] : Wls[k * 64 + (n - 64)];
    Wt[n * 128 + k] = f2bf(v);
}

// ---- gather 16 rows/wave of prescaled bf16 table into As (LDS) ----
// y[node] = dinv[node] * ( sum_{s in N(node)} tab[s] + tab[node] ), tab prescaled by dinv[src]
// lane handles feats {2*lane, 2*lane+1}; edge loop unrolled x4 for MLP.
__device__ __forceinline__ void gather16(
    const unsigned short* __restrict__ tab,
    const int* __restrict__ off, const int* __restrict__ csr,
    const float* __restrict__ dinv,
    unsigned short* As, int r0, int wave, int lane, int nrows) {
    for (int i = 0; i < 16; ++i) {
        int row = wave * 16 + i;
        int node = r0 + row;
        unsigned int stv = 0;
        if (node < nrows) {
            unsigned int p = *(const unsigned int*)(tab + (size_t)node * 128 + lane * 2);
            float accx = bf2f((unsigned short)(p & 0xffffu));
            float accy = bf2f((unsigned short)(p >> 16));
            int b = __builtin_amdgcn_readfirstlane(off[node]);
            int e = __builtin_amdgcn_readfirstlane(off[node + 1]);
            int t = b;
            for (; t + 4 <= e; t += 4) {
                int s0 = csr[t], s1 = csr[t + 1], s2 = csr[t + 2], s3 = csr[t + 3];
                unsigned int q0 = *(const unsigned int*)(tab + (size_t)s0 * 128 + lane * 2);
                unsigned int q1 = *(const unsigned int*)(tab + (size_t)s1 * 128 + lane * 2);
                unsigned int q2 = *(const unsigned int*)(tab + (size_t)s2 * 128 + lane * 2);
                unsigned int q3 = *(const unsigned int*)(tab + (size_t)s3 * 128 + lane * 2);
                accx += bf2f((unsigned short)(q0 & 0xffffu)) + bf2f((unsigned short)(q1 & 0xffffu))
                      + bf2f((unsigned short)(q2 & 0xffffu)) + bf2f((unsigned short)(q3 & 0xffffu));
                accy += bf2f((unsigned short)(q0 >> 16)) + bf2f((unsigned short)(q1 >> 16))
                      + bf2f((unsigned short)(q2 >> 16)) + bf2f((unsigned short)(q3 >> 16));
            }
            for (; t < e; ++t) {
                int s = csr[t];
                unsigned int q = *(const unsigned int*)(tab + (size_t)s * 128 + lane * 2);
                accx += bf2f((unsigned short)(q & 0xffffu));
                accy += bf2f((unsigned short)(q >> 16));
            }
            float di = dinv[node];
            stv = ((unsigned int)f2bf(accy * di) << 16) | (unsigned int)f2bf(accx * di);
        }
        *(unsigned int*)(As + row * 136 + lane * 2) = stv;
    }
}

// ---------------- fused 1: h = (A_norm @ x) @ W1 + b1, stored prescaled bf16 ----------------
// block: 256 thr (4 waves), 64 rows; wave w covers cols {16w..16w+15} and {64+16w..}.
__global__ __launch_bounds__(256) void k_fused1(
    const unsigned short* __restrict__ xs,   // [NN][128] bf16 prescaled
    const int* __restrict__ off, const int* __restrict__ csr,
    const float* __restrict__ dinv,
    const unsigned short* __restrict__ Bt,   // [128][128] bf16 W1t (n-major, k-contig)
    const float* __restrict__ bias,          // [128] f32
    unsigned short* __restrict__ hs,         // [NN][128] bf16, prescaled by dinv
    int nrows) {
    __shared__ __align__(16) unsigned short As[64 * 136];
    int tid = threadIdx.x;
    int lane = tid & 63, wave = tid >> 6;
    int r0 = blockIdx.x * 64;
    gather16(xs, off, csr, dinv, As, r0, wave, lane, nrows);
    __syncthreads();
    int quad = lane >> 4, l16 = lane & 15;
    int c0 = wave * 16 + l16;        // first col tile
    int c1 = 64 + wave * 16 + l16;   // second col tile
    float4v acc[4][2];
#pragma unroll
    for (int rt = 0; rt < 4; ++rt) {
        float4v z = {0.f, 0.f, 0.f, 0.f};
        acc[rt][0] = z; acc[rt][1] = z;
    }
#pragma unroll
    for (int ks = 0; ks < 4; ++ks) {
        short8 b0 = *(const short8*)(Bt + (size_t)c0 * 128 + ks * 32 + quad * 8);
        short8 b1 = *(const short8*)(Bt + (size_t)c1 * 128 + ks * 32 + quad * 8);
        short8 af[4];
#pragma unroll
        for (int rt = 0; rt < 4; ++rt)
            af[rt] = *(const short8*)(As + (rt * 16 + l16) * 136 + ks * 32 + quad * 8);
#pragma unroll
        for (int rt = 0; rt < 4; ++rt) {
            acc[rt][0] = __builtin_amdgcn_mfma_f32_16x16x32_bf16(af[rt], b0, acc[rt][0], 0, 0, 0);
            acc[rt][1] = __builtin_amdgcn_mfma_f32_16x16x32_bf16(af[rt], b1, acc[rt][1], 0, 0, 0);
        }
    }
    float bc0 = bias[c0], bc1 = bias[c1];
#pragma unroll
    for (int rt = 0; rt < 4; ++rt)
#pragma unroll
        for (int reg = 0; reg < 4; ++reg) {
            int gr = r0 + rt * 16 + quad * 4 + reg;
            if (gr < nrows) {
                float dg = dinv[gr];
                hs[(size_t)gr * 128 + c0] = f2bf(dg * (acc[rt][0][reg] + bc0));
                hs[(size_t)gr * 128 + c1] = f2bf(dg * (acc[rt][1][reg] + bc1));
            }
        }
}

// ---------- fused 2: [mu|ls] = (A_norm @ h) @ W2t + [bmu|bls]; out = mu + init*exp(ls) ----------
// wave w: mu cols {16w..16w+15} (B rows c0) and ls cols (B rows c0+64) -> in-register epilogue.
__global__ __launch_bounds__(256) void k_fused2(
    const unsigned short* __restrict__ hsc,  // [NN][128] bf16 prescaled
    const int* __restrict__ off, const int* __restrict__ csr,
    const float* __restrict__ dinv,
    const unsigned short* __restrict__ Bt,   // [128][128] bf16 W2t ([0:64)=Wmu cols, [64:128)=Wls cols)
    const float* __restrict__ bmu,           // [64] f32
    const float* __restrict__ bls,           // [64] f32
    const float* __restrict__ init,          // [NN][64] f32
    float* __restrict__ outp,                // [NN][64] f32
    int nrows) {
    __shared__ __align__(16) unsigned short As[64 * 136];
    int tid = threadIdx.x;
    int lane = tid & 63, wave = tid >> 6;
    int r0 = blockIdx.x * 64;
    gather16(hsc, off, csr, dinv, As, r0, wave, lane, nrows);
    __syncthreads();
    int quad = lane >> 4, l16 = lane & 15;
    int cm = wave * 16 + l16;        // mu col (0..63)
    int cl = 64 + cm;                // matching ls col
    float4v acc[4][2];
#pragma unroll
    for (int rt = 0; rt < 4; ++rt) {
        float4v z = {0.f, 0.f, 0.f, 0.f};
        acc[rt][0] = z; acc[rt][1] = z;
    }
#pragma unroll
    for (int ks = 0; ks < 4; ++ks) {
        short8 b0 = *(const short8*)(Bt + (size_t)cm * 128 + ks * 32 + quad * 8);
        short8 b1 = *(const short8*)(Bt + (size_t)cl * 128 + ks * 32 + quad * 8);
        short8 af[4];
#pragma unroll
        for (int rt = 0; rt < 4; ++rt)
            af[rt] = *(const short8*)(As + (rt * 16 + l16) * 136 + ks * 32 + quad * 8);
#pragma unroll
        for (int rt = 0; rt < 4; ++rt) {
            acc[rt][0] = __builtin_amdgcn_mfma_f32_16x16x32_bf16(af[rt], b0, acc[rt][0], 0, 0, 0);
            acc[rt][1] = __builtin_amdgcn_mfma_f32_16x16x32_bf16(af[rt], b1, acc[rt][1], 0, 0, 0);
        }
    }
    float bc_mu = bmu[cm], bc_ls = bls[cm];
#pragma unroll
    for (int rt = 0; rt < 4; ++rt)
#pragma unroll
        for (int reg = 0; reg < 4; ++reg) {
            int gr = r0 + rt * 16 + quad * 4 + reg;
            if (gr < nrows) {
                float mu = acc[rt][0][reg] + bc_mu;
                float ls = acc[rt][1][reg] + bc_ls;
                float idv = init[(size_t)gr * 64 + cm];
                outp[(size_t)gr * 64 + cm] = mu + idv * expf(ls);
            }
        }
}

extern "C" void kernel_launch(void* const* d_in, const int* in_sizes, int n_in,
                              void* d_out, int out_size, void* d_ws, size_t ws_size,
                              hipStream_t stream) {
    const float* x   = (const float*)d_in[0];  // [N,128] f32
    const int*   ei  = (const int*)d_in[1];    // [2,E] int32
    const float* ind = (const float*)d_in[2];  // [N,64] f32
    const float* W1  = (const float*)d_in[3];  // [128,128] f32
    const float* b1  = (const float*)d_in[4];  // [128] f32
    const float* Wmu = (const float*)d_in[5];  // [128,64] f32
    const float* bmu = (const float*)d_in[6];  // [64] f32
    const float* Wls = (const float*)d_in[7];  // [128,64] f32
    const float* bls = (const float*)d_in[8];  // [64] f32
    float* outp = (float*)d_out;               // [N,64] f32

    char* w = (char*)d_ws;
    auto carve = [&](size_t bytes) -> char* {
        char* p = w; w += (bytes + 255) & ~(size_t)255; return p;
    };
    int*   cnt  = (int*)carve((size_t)NN * 4);        // doubles as cursor after scan
    int*   off  = (int*)carve((size_t)(NN + 1) * 4);
    float* dinv = (float*)carve((size_t)NN * 4);
    int*   csr  = (int*)carve((size_t)NE * 4);
    unsigned short* W1t = (unsigned short*)carve(128 * 128 * 2);
    unsigned short* W2t = (unsigned short*)carve(128 * 128 * 2);
    unsigned short* xs  = (unsigned short*)carve((size_t)NN * 128 * 2);
    unsigned short* hs  = (unsigned short*)carve((size_t)NN * 128 * 2);
    // total ~59 MB of ws (fit confirmed by round-3 pass at 33 MB; xs adds 25.6 MB)

    k_zero<<<391, 256, 0, stream>>>(cnt, NN);
    k_w1t<<<64, 256, 0, stream>>>(W1, W1t);
    k_w2t<<<64, 256, 0, stream>>>(Wmu, Wls, W2t);
    k_count<<<(NE + 255) / 256, 256, 0, stream>>>(ei + NE, cnt);
    k_dinv<<<391, 256, 0, stream>>>(cnt, dinv);
    k_scan<<<1, 1024, 0, stream>>>(cnt, off);
    k_zero<<<391, 256, 0, stream>>>(cnt, NN);  // reuse cnt as fill cursor
    k_fill<<<(NE + 255) / 256, 256, 0, stream>>>(ei, off, cnt, csr);
    k_prescale<<<(NN * 32 + 255) / 256, 256, 0, stream>>>(x, dinv, xs);
    k_fused1<<<(NN + 63) / 64, 256, 0, stream>>>(xs, off, csr, dinv, W1t, b1, hs, NN);
    k_fused2<<<(NN + 63) / 64, 256, 0, stream>>>(hs, off, csr, dinv, W2t, bmu, bls, ind, outp, NN);
}

// Round 5
// 455.050 us; speedup vs baseline: 2.9419x; 1.3798x over previous
//
#include <hip/hip_runtime.h>
#include <hip/hip_bf16.h>
#include <math.h>

#define NN 100000
#define NE 1600000

// bf16 <-> f32 helpers (bf16 stored as raw ushort; value<<16 == f32 bits)
__device__ __forceinline__ float bf2f(unsigned short u) {
    union { unsigned int u; float f; } c; c.u = ((unsigned int)u) << 16; return c.f;
}
__device__ __forceinline__ unsigned short f2bf(float f) {
    union { float f; unsigned int u; } c; c.f = f;
    unsigned int x = c.u;
    return (unsigned short)((x + 0x7fffu + ((x >> 16) & 1u)) >> 16); // RNE
}

typedef __attribute__((ext_vector_type(8))) short short8;
typedef __attribute__((ext_vector_type(4))) float float4v;

// ---------------- CSR build ----------------

__global__ void k_count(const int* __restrict__ dst, int* __restrict__ cnt) {
    int e = blockIdx.x * blockDim.x + threadIdx.x;
    if (e < NE) {
        int d = dst[e];
        if ((unsigned)d < (unsigned)NN) atomicAdd(&cnt[d], 1);
    }
}

// ---- hierarchical exclusive scan of cnt[NN] -> off[NN+1], plus dinv ----
// Phase A: 98 blocks x 256 thr, 4 elems/thr (1024/block): per-block exclusive
// scan into off, block total -> bsum, and dinv[i] = rsqrt(cnt[i]+1).
__global__ __launch_bounds__(256) void k_scanA(const int* __restrict__ cnt,
        int* __restrict__ off, int* __restrict__ bsum, float* __restrict__ dinv) {
    __shared__ int s[256];
    int t = threadIdx.x;
    int i0 = blockIdx.x * 1024 + t * 4;
    int v[4]; int tot = 0;
#pragma unroll
    for (int j = 0; j < 4; ++j) {
        int i = i0 + j;
        int c = (i < NN) ? cnt[i] : 0;
        v[j] = c; tot += c;
        if (i < NN) dinv[i] = rsqrtf((float)(c + 1));
    }
    s[t] = tot;
    __syncthreads();
    for (int d = 1; d < 256; d <<= 1) {
        int x = (t >= d) ? s[t - d] : 0;
        __syncthreads();
        s[t] += x;
        __syncthreads();
    }
    int run = s[t] - tot;  // exclusive within block
#pragma unroll
    for (int j = 0; j < 4; ++j) { int i = i0 + j; if (i < NN) off[i] = run; run += v[j]; }
    if (t == 255) bsum[blockIdx.x] = s[255];
}

// Phase B: single block scans the 98 block sums (exclusive, in place); off[NN]=total.
__global__ __launch_bounds__(128) void k_scanB(int* __restrict__ bsum, int* __restrict__ off) {
    __shared__ int s[128];
    int t = threadIdx.x;
    int v = (t < 98) ? bsum[t] : 0;
    s[t] = v;
    __syncthreads();
    for (int d = 1; d < 128; d <<= 1) {
        int x = (t >= d) ? s[t - d] : 0;
        __syncthreads();
        s[t] += x;
        __syncthreads();
    }
    if (t < 98) bsum[t] = s[t] - v;  // exclusive base per chunk
    if (t == 127) off[NN] = s[127];
}

// Phase C: add chunk bases.
__global__ void k_scanC(int* __restrict__ off, const int* __restrict__ bsum) {
    int i = blockIdx.x * 256 + threadIdx.x;
    if (i < NN) off[i] += bsum[i >> 10];
}

// cursor aliases cnt (re-zeroed after scan)
__global__ void k_fill(const int* __restrict__ ei, const int* __restrict__ off,
                       int* __restrict__ cursor, int* __restrict__ csr) {
    int e = blockIdx.x * blockDim.x + threadIdx.x;
    if (e >= NE) return;
    int s = ei[e];
    int d = ei[NE + e];
    if ((unsigned)d >= (unsigned)NN) return;
    int pos = off[d] + atomicAdd(&cursor[d], 1);
    if ((unsigned)pos < (unsigned)NE) csr[pos] = s;
}

// ---------------- prescale: xs[i][j] = bf16(dinv[i] * x[i][j]) ----------------
__global__ __launch_bounds__(256) void k_prescale(const float* __restrict__ x,
        const float* __restrict__ dinv, unsigned short* __restrict__ xs) {
    int i = blockIdx.x * 256 + threadIdx.x;   // NN*32 threads, 4 feats each
    if (i >= NN * 32) return;
    int node = i >> 5, c = (i & 31) << 2;
    float d = dinv[node];
    float4 v = *(const float4*)(x + (size_t)node * 128 + c);
    uint2 st;
    st.x = ((unsigned int)f2bf(d * v.y) << 16) | f2bf(d * v.x);
    st.y = ((unsigned int)f2bf(d * v.w) << 16) | f2bf(d * v.z);
    *(uint2*)(xs + (size_t)node * 128 + c) = st;
}

// ---------------- merged weight transpose + downcast ----------------
__global__ void k_wt(const float* __restrict__ W1, const float* __restrict__ Wmu,
                     const float* __restrict__ Wls,
                     unsigned short* __restrict__ W1t, unsigned short* __restrict__ W2t) {
    int idx = blockIdx.x * 256 + threadIdx.x;   // 32768
    if (idx < 16384) {
        int n = idx >> 7, k = idx & 127;
        W1t[n * 128 + k] = f2bf(W1[k * 128 + n]);          // W1 [128][128]
    } else {
        int j = idx - 16384;
        int n = j >> 7, k = j & 127;                       // Wmu/Wls [128][64]
        float v = (n < 64) ? Wmu[k * 64 + n] : Wls[k * 64 + (n - 64)];
        W2t[n * 128 + k] = f2bf(v);
    }
}

// ---------------- gather: one wave per node ----------------
// y[node] = dinv[node] * ( tab[node] + sum_{s in N(node)} tab[s] ), tab prescaled by dinv[src]
// lane owns feats {2*lane, 2*lane+1}; edge loop unrolled x8 (csr reads are wave-uniform -> scalar).
__global__ __launch_bounds__(256) void k_gather(
    const unsigned short* __restrict__ tab,
    const int* __restrict__ off, const int* __restrict__ csr,
    const float* __restrict__ dinv,
    unsigned short* __restrict__ yout) {
    int node = blockIdx.x * 4 + (threadIdx.x >> 6);
    int lane = threadIdx.x & 63;
    if (node >= NN) return;
    unsigned int p = *(const unsigned int*)(tab + (size_t)node * 128 + lane * 2);
    float ax = bf2f((unsigned short)(p & 0xffffu));
    float ay = bf2f((unsigned short)(p >> 16));
    int b = __builtin_amdgcn_readfirstlane(off[node]);
    int e = __builtin_amdgcn_readfirstlane(off[node + 1]);
    int t = b;
    for (; t + 8 <= e; t += 8) {
        int si[8]; unsigned int q[8];
#pragma unroll
        for (int j = 0; j < 8; ++j) si[j] = csr[t + j];
#pragma unroll
        for (int j = 0; j < 8; ++j)
            q[j] = *(const unsigned int*)(tab + (size_t)si[j] * 128 + lane * 2);
#pragma unroll
        for (int j = 0; j < 8; ++j) {
            ax += bf2f((unsigned short)(q[j] & 0xffffu));
            ay += bf2f((unsigned short)(q[j] >> 16));
        }
    }
    for (; t < e; ++t) {
        int s = csr[t];
        unsigned int q = *(const unsigned int*)(tab + (size_t)s * 128 + lane * 2);
        ax += bf2f((unsigned short)(q & 0xffffu));
        ay += bf2f((unsigned short)(q >> 16));
    }
    float di = dinv[node];
    unsigned int stv = ((unsigned int)f2bf(ay * di) << 16) | (unsigned int)f2bf(ax * di);
    *(unsigned int*)(yout + (size_t)node * 128 + lane * 2) = stv;
}

// ---------------- GEMM1 (in-place): hs = bf16(dinv * (y @ W1 + b1)) ----------------
// yio: read y rows [r0,r0+64) into LDS, later overwrite same rows with prescaled h.
__global__ __launch_bounds__(256) void k_gemm1(
    unsigned short* __restrict__ yio,        // [NN][128] bf16 (y1 in, hs out)
    const unsigned short* __restrict__ Bt,   // [128][128] bf16 W1t (n-major, k-contig)
    const float* __restrict__ bias,          // [128] f32
    const float* __restrict__ dinv,
    int nrows) {
    __shared__ __align__(16) unsigned short As[64 * 136];
    int tid = threadIdx.x;
    int r0 = blockIdx.x * 64;
    for (int c = tid; c < 1024; c += 256) {
        int row = c >> 4, kc = (c & 15) << 3;
        int gr = r0 + row;
        short8 v = {0, 0, 0, 0, 0, 0, 0, 0};
        if (gr < nrows) v = *(const short8*)(yio + (size_t)gr * 128 + kc);
        *(short8*)(As + row * 136 + kc) = v;
    }
    __syncthreads();
    int lane = tid & 63, wave = tid >> 6;
    int quad = lane >> 4, l16 = lane & 15;
    int c0 = wave * 16 + l16;        // cols 0..63
    int c1 = 64 + c0;                // cols 64..127
    float4v acc[4][2];
#pragma unroll
    for (int rt = 0; rt < 4; ++rt) {
        float4v z = {0.f, 0.f, 0.f, 0.f};
        acc[rt][0] = z; acc[rt][1] = z;
    }
#pragma unroll
    for (int ks = 0; ks < 4; ++ks) {
        short8 b0 = *(const short8*)(Bt + (size_t)c0 * 128 + ks * 32 + quad * 8);
        short8 b1 = *(const short8*)(Bt + (size_t)c1 * 128 + ks * 32 + quad * 8);
        short8 af[4];
#pragma unroll
        for (int rt = 0; rt < 4; ++rt)
            af[rt] = *(const short8*)(As + (rt * 16 + l16) * 136 + ks * 32 + quad * 8);
#pragma unroll
        for (int rt = 0; rt < 4; ++rt) {
            acc[rt][0] = __builtin_amdgcn_mfma_f32_16x16x32_bf16(af[rt], b0, acc[rt][0], 0, 0, 0);
            acc[rt][1] = __builtin_amdgcn_mfma_f32_16x16x32_bf16(af[rt], b1, acc[rt][1], 0, 0, 0);
        }
    }
    float bc0 = bias[c0], bc1 = bias[c1];
#pragma unroll
    for (int rt = 0; rt < 4; ++rt)
#pragma unroll
        for (int reg = 0; reg < 4; ++reg) {
            int gr = r0 + rt * 16 + quad * 4 + reg;
            if (gr < nrows) {
                float dg = dinv[gr];
                yio[(size_t)gr * 128 + c0] = f2bf(dg * (acc[rt][0][reg] + bc0));
                yio[(size_t)gr * 128 + c1] = f2bf(dg * (acc[rt][1][reg] + bc1));
            }
        }
}

// ---------- GEMM2 + epilogue: [mu|ls] = y2 @ W2t + [bmu|bls]; out = mu + init*exp(ls) ----------
// wave w: mu cols {16w..16w+15} and matching ls cols -> in-register epilogue.
__global__ __launch_bounds__(256) void k_gemm2(
    const unsigned short* __restrict__ y2,   // [NN][128] bf16
    const unsigned short* __restrict__ Bt,   // [128][128] bf16 W2t
    const float* __restrict__ bmu,           // [64] f32
    const float* __restrict__ bls,           // [64] f32
    const float* __restrict__ init,          // [NN][64] f32
    float* __restrict__ outp,                // [NN][64] f32
    int nrows) {
    __shared__ __align__(16) unsigned short As[64 * 136];
    int tid = threadIdx.x;
    int r0 = blockIdx.x * 64;
    for (int c = tid; c < 1024; c += 256) {
        int row = c >> 4, kc = (c & 15) << 3;
        int gr = r0 + row;
        short8 v = {0, 0, 0, 0, 0, 0, 0, 0};
        if (gr < nrows) v = *(const short8*)(y2 + (size_t)gr * 128 + kc);
        *(short8*)(As + row * 136 + kc) = v;
    }
    __syncthreads();
    int lane = tid & 63, wave = tid >> 6;
    int quad = lane >> 4, l16 = lane & 15;
    int cm = wave * 16 + l16;        // mu col (0..63)
    int cl = 64 + cm;                // matching ls col
    float4v acc[4][2];
#pragma unroll
    for (int rt = 0; rt < 4; ++rt) {
        float4v z = {0.f, 0.f, 0.f, 0.f};
        acc[rt][0] = z; acc[rt][1] = z;
    }
#pragma unroll
    for (int ks = 0; ks < 4; ++ks) {
        short8 b0 = *(const short8*)(Bt + (size_t)cm * 128 + ks * 32 + quad * 8);
        short8 b1 = *(const short8*)(Bt + (size_t)cl * 128 + ks * 32 + quad * 8);
        short8 af[4];
#pragma unroll
        for (int rt = 0; rt < 4; ++rt)
            af[rt] = *(const short8*)(As + (rt * 16 + l16) * 136 + ks * 32 + quad * 8);
#pragma unroll
        for (int rt = 0; rt < 4; ++rt) {
            acc[rt][0] = __builtin_amdgcn_mfma_f32_16x16x32_bf16(af[rt], b0, acc[rt][0], 0, 0, 0);
            acc[rt][1] = __builtin_amdgcn_mfma_f32_16x16x32_bf16(af[rt], b1, acc[rt][1], 0, 0, 0);
        }
    }
    float bc_mu = bmu[cm], bc_ls = bls[cm];
#pragma unroll
    for (int rt = 0; rt < 4; ++rt)
#pragma unroll
        for (int reg = 0; reg < 4; ++reg) {
            int gr = r0 + rt * 16 + quad * 4 + reg;
            if (gr < nrows) {
                float mu = acc[rt][0][reg] + bc_mu;
                float ls = acc[rt][1][reg] + bc_ls;
                float idv = init[(size_t)gr * 64 + cm];
                outp[(size_t)gr * 64 + cm] = mu + idv * expf(ls);
            }
        }
}

extern "C" void kernel_launch(void* const* d_in, const int* in_sizes, int n_in,
                              void* d_out, int out_size, void* d_ws, size_t ws_size,
                              hipStream_t stream) {
    const float* x   = (const float*)d_in[0];  // [N,128] f32
    const int*   ei  = (const int*)d_in[1];    // [2,E] int32
    const float* ind = (const float*)d_in[2];  // [N,64] f32
    const float* W1  = (const float*)d_in[3];  // [128,128] f32
    const float* b1  = (const float*)d_in[4];  // [128] f32
    const float* Wmu = (const float*)d_in[5];  // [128,64] f32
    const float* bmu = (const float*)d_in[6];  // [64] f32
    const float* Wls = (const float*)d_in[7];  // [128,64] f32
    const float* bls = (const float*)d_in[8];  // [64] f32
    float* outp = (float*)d_out;               // [N,64] f32

    char* w = (char*)d_ws;
    auto carve = [&](size_t bytes) -> char* {
        char* p = w; w += (bytes + 255) & ~(size_t)255; return p;
    };
    int*   cnt  = (int*)carve((size_t)NN * 4);        // doubles as fill cursor
    int*   off  = (int*)carve((size_t)(NN + 1) * 4);
    int*   bsum = (int*)carve(128 * 4);
    float* dinv = (float*)carve((size_t)NN * 4);
    int*   csr  = (int*)carve((size_t)NE * 4);
    unsigned short* W1t = (unsigned short*)carve(128 * 128 * 2);
    unsigned short* W2t = (unsigned short*)carve(128 * 128 * 2);
    unsigned short* xs  = (unsigned short*)carve((size_t)NN * 128 * 2);  // xs, then y2
    unsigned short* y   = (unsigned short*)carve((size_t)NN * 128 * 2);  // y1, then hs (in-place)
    // total ~59 MB of ws (round-4 footprint, proven to fit)

    hipMemsetAsync(cnt, 0, (size_t)NN * 4, stream);
    k_wt<<<128, 256, 0, stream>>>(W1, Wmu, Wls, W1t, W2t);
    k_count<<<(NE + 255) / 256, 256, 0, stream>>>(ei + NE, cnt);
    k_scanA<<<98, 256, 0, stream>>>(cnt, off, bsum, dinv);
    k_scanB<<<1, 128, 0, stream>>>(bsum, off);
    k_scanC<<<391, 256, 0, stream>>>(off, bsum);
    hipMemsetAsync(cnt, 0, (size_t)NN * 4, stream);   // reuse cnt as fill cursor
    k_fill<<<(NE + 255) / 256, 256, 0, stream>>>(ei, off, cnt, csr);
    k_prescale<<<(NN * 32 + 255) / 256, 256, 0, stream>>>(x, dinv, xs);
    k_gather<<<(NN + 3) / 4, 256, 0, stream>>>(xs, off, csr, dinv, y);      // y1
    k_gemm1<<<(NN + 63) / 64, 256, 0, stream>>>(y, W1t, b1, dinv, NN);      // y -> hs in place
    k_gather<<<(NN + 3) / 4, 256, 0, stream>>>(y, off, csr, dinv, xs);      // y2 into xs
    k_gemm2<<<(NN + 63) / 64, 256, 0, stream>>>(xs, W2t, bmu, bls, ind, outp, NN);
}

// Round 6
// 415.353 us; speedup vs baseline: 3.2231x; 1.0956x over previous
//
#include <hip/hip_runtime.h>
#include <hip/hip_bf16.h>
#include <math.h>

#define NN 100000
#define NE 1600000

// bf16 <-> f32 helpers (bf16 stored as raw ushort; value<<16 == f32 bits)
__device__ __forceinline__ float bf2f(unsigned int u) {
    union { unsigned int u; float f; } c; c.u = u << 16; return c.f;
}
__device__ __forceinline__ unsigned short f2bf(float f) {
    union { float f; unsigned int u; } c; c.f = f;
    unsigned int x = c.u;
    return (unsigned short)((x + 0x7fffu + ((x >> 16) & 1u)) >> 16); // RNE
}

typedef __attribute__((ext_vector_type(8))) short short8;
typedef __attribute__((ext_vector_type(4))) float float4v;

// ---------------- CSR build ----------------

// count + per-edge rank in one pass (the count atomic returns the rank for free)
__global__ __launch_bounds__(256) void k_count_rank(const int* __restrict__ dst,
        int* __restrict__ cnt, int* __restrict__ rank) {
    int e0 = (blockIdx.x * 256 + threadIdx.x) * 4;   // NE % 4 == 0
    if (e0 >= NE) return;
    int4 d = *(const int4*)(dst + e0);
    int4 r;
    r.x = atomicAdd(&cnt[d.x], 1);
    r.y = atomicAdd(&cnt[d.y], 1);
    r.z = atomicAdd(&cnt[d.z], 1);
    r.w = atomicAdd(&cnt[d.w], 1);
    *(int4*)(rank + e0) = r;
}

// ---- hierarchical exclusive scan of cnt[NN] -> off[NN+1], plus dinv ----
__global__ __launch_bounds__(256) void k_scanA(const int* __restrict__ cnt,
        int* __restrict__ off, int* __restrict__ bsum, float* __restrict__ dinv) {
    __shared__ int s[256];
    int t = threadIdx.x;
    int i0 = blockIdx.x * 1024 + t * 4;
    int v[4]; int tot = 0;
#pragma unroll
    for (int j = 0; j < 4; ++j) {
        int i = i0 + j;
        int c = (i < NN) ? cnt[i] : 0;
        v[j] = c; tot += c;
        if (i < NN) dinv[i] = rsqrtf((float)(c + 1));
    }
    s[t] = tot;
    __syncthreads();
    for (int d = 1; d < 256; d <<= 1) {
        int x = (t >= d) ? s[t - d] : 0;
        __syncthreads();
        s[t] += x;
        __syncthreads();
    }
    int run = s[t] - tot;  // exclusive within block
#pragma unroll
    for (int j = 0; j < 4; ++j) { int i = i0 + j; if (i < NN) off[i] = run; run += v[j]; }
    if (t == 255) bsum[blockIdx.x] = s[255];
}

__global__ __launch_bounds__(128) void k_scanB(int* __restrict__ bsum, int* __restrict__ off) {
    __shared__ int s[128];
    int t = threadIdx.x;
    int v = (t < 98) ? bsum[t] : 0;
    s[t] = v;
    __syncthreads();
    for (int d = 1; d < 128; d <<= 1) {
        int x = (t >= d) ? s[t - d] : 0;
        __syncthreads();
        s[t] += x;
        __syncthreads();
    }
    if (t < 98) bsum[t] = s[t] - v;  // exclusive base per chunk
    if (t == 127) off[NN] = s[127];
}

__global__ void k_scanC(int* __restrict__ off, const int* __restrict__ bsum) {
    int i = blockIdx.x * 256 + threadIdx.x;
    if (i < NN) off[i] += bsum[i >> 10];
}

// pure scatter fill: no atomics, 4 edges/thread, int4 loads
__global__ __launch_bounds__(256) void k_fill2(const int* __restrict__ ei,
        const int* __restrict__ off, const int* __restrict__ rank, int* __restrict__ csr) {
    int e0 = (blockIdx.x * 256 + threadIdx.x) * 4;
    if (e0 >= NE) return;
    int4 s = *(const int4*)(ei + e0);
    int4 d = *(const int4*)(ei + NE + e0);
    int4 r = *(const int4*)(rank + e0);
    csr[off[d.x] + r.x] = s.x;
    csr[off[d.y] + r.y] = s.y;
    csr[off[d.z] + r.z] = s.z;
    csr[off[d.w] + r.w] = s.w;
}

// ---------------- prescale: xs[i][j] = bf16(dinv[i] * x[i][j]) ----------------
__global__ __launch_bounds__(256) void k_prescale(const float* __restrict__ x,
        const float* __restrict__ dinv, unsigned short* __restrict__ xs) {
    int i = blockIdx.x * 256 + threadIdx.x;   // NN*32 threads, 4 feats each
    if (i >= NN * 32) return;
    int node = i >> 5, c = (i & 31) << 2;
    float d = dinv[node];
    float4 v = *(const float4*)(x + (size_t)node * 128 + c);
    uint2 st;
    st.x = ((unsigned int)f2bf(d * v.y) << 16) | f2bf(d * v.x);
    st.y = ((unsigned int)f2bf(d * v.w) << 16) | f2bf(d * v.z);
    *(uint2*)(xs + (size_t)node * 128 + c) = st;
}

// ---------------- merged weight transpose + downcast ----------------
__global__ void k_wt(const float* __restrict__ W1, const float* __restrict__ Wmu,
                     const float* __restrict__ Wls,
                     unsigned short* __restrict__ W1t, unsigned short* __restrict__ W2t) {
    int idx = blockIdx.x * 256 + threadIdx.x;   // 32768
    if (idx < 16384) {
        int n = idx >> 7, k = idx & 127;
        W1t[n * 128 + k] = f2bf(W1[k * 128 + n]);          // W1 [128][128]
    } else {
        int j = idx - 16384;
        int n = j >> 7, k = j & 127;                       // Wmu/Wls [128][64]
        float v = (n < 64) ? Wmu[k * 64 + n] : Wls[k * 64 + (n - 64)];
        W2t[n * 128 + k] = f2bf(v);
    }
}

// ---------------- gather: one wave per node, half-waves pair up on edges ----------------
// y[node] = dinv[node] * ( tab[node] + sum_{s in N(node)} tab[s] ), tab prescaled by dinv[src]
// lanes 0-31 take even edge slots, lanes 32-63 odd; each lane covers 4 feats (8B loads).
// One global_load_dwordx2 fetches TWO neighbor rows (512B across the wave).
__global__ __launch_bounds__(256) void k_gather(
    const unsigned short* __restrict__ tab,
    const int* __restrict__ off, const int* __restrict__ csr,
    const float* __restrict__ dinv,
    unsigned short* __restrict__ yout) {
    int node = blockIdx.x * 4 + (threadIdx.x >> 6);   // NN % 4 == 0 -> exact grid
    int lane = threadIdx.x & 63;
    int half = lane >> 5, l32 = lane & 31;
    float a0 = 0.f, a1 = 0.f, a2 = 0.f, a3 = 0.f;
    if (half == 0) {  // self term once
        uint2 p = *(const uint2*)(tab + (size_t)node * 128 + l32 * 4);
        a0 = bf2f(p.x & 0xffffu); a1 = bf2f(p.x >> 16);
        a2 = bf2f(p.y & 0xffffu); a3 = bf2f(p.y >> 16);
    }
    int b = __builtin_amdgcn_readfirstlane(off[node]);
    int e = __builtin_amdgcn_readfirstlane(off[node + 1]);
    int t = b + half;
    while (t + 6 < e) {  // 4 edges per half per iter (8 edges/wave, 4 loads/lane)
        int s0 = csr[t], s1 = csr[t + 2], s2 = csr[t + 4], s3 = csr[t + 6];
        uint2 q0 = *(const uint2*)(tab + (size_t)s0 * 128 + l32 * 4);
        uint2 q1 = *(const uint2*)(tab + (size_t)s1 * 128 + l32 * 4);
        uint2 q2 = *(const uint2*)(tab + (size_t)s2 * 128 + l32 * 4);
        uint2 q3 = *(const uint2*)(tab + (size_t)s3 * 128 + l32 * 4);
        a0 += bf2f(q0.x & 0xffffu) + bf2f(q1.x & 0xffffu) + bf2f(q2.x & 0xffffu) + bf2f(q3.x & 0xffffu);
        a1 += bf2f(q0.x >> 16)     + bf2f(q1.x >> 16)     + bf2f(q2.x >> 16)     + bf2f(q3.x >> 16);
        a2 += bf2f(q0.y & 0xffffu) + bf2f(q1.y & 0xffffu) + bf2f(q2.y & 0xffffu) + bf2f(q3.y & 0xffffu);
        a3 += bf2f(q0.y >> 16)     + bf2f(q1.y >> 16)     + bf2f(q2.y >> 16)     + bf2f(q3.y >> 16);
        t += 8;
    }
    while (t < e) {
        int s = csr[t];
        uint2 q = *(const uint2*)(tab + (size_t)s * 128 + l32 * 4);
        a0 += bf2f(q.x & 0xffffu); a1 += bf2f(q.x >> 16);
        a2 += bf2f(q.y & 0xffffu); a3 += bf2f(q.y >> 16);
        t += 2;
    }
    // combine even/odd halves
    a0 += __shfl_xor(a0, 32);
    a1 += __shfl_xor(a1, 32);
    a2 += __shfl_xor(a2, 32);
    a3 += __shfl_xor(a3, 32);
    if (half == 0) {
        float di = dinv[node];
        uint2 st;
        st.x = ((unsigned int)f2bf(a1 * di) << 16) | f2bf(a0 * di);
        st.y = ((unsigned int)f2bf(a3 * di) << 16) | f2bf(a2 * di);
        *(uint2*)(yout + (size_t)node * 128 + l32 * 4) = st;
    }
}

// ---------------- GEMM1 (in-place): hs = bf16(dinv * (y @ W1 + b1)) ----------------
__global__ __launch_bounds__(256) void k_gemm1(
    unsigned short* __restrict__ yio,        // [NN][128] bf16 (y1 in, hs out)
    const unsigned short* __restrict__ Bt,   // [128][128] bf16 W1t (n-major, k-contig)
    const float* __restrict__ bias,          // [128] f32
    const float* __restrict__ dinv,
    int nrows) {
    __shared__ __align__(16) unsigned short As[64 * 136];
    int tid = threadIdx.x;
    int r0 = blockIdx.x * 64;
    for (int c = tid; c < 1024; c += 256) {
        int row = c >> 4, kc = (c & 15) << 3;
        int gr = r0 + row;
        short8 v = {0, 0, 0, 0, 0, 0, 0, 0};
        if (gr < nrows) v = *(const short8*)(yio + (size_t)gr * 128 + kc);
        *(short8*)(As + row * 136 + kc) = v;
    }
    __syncthreads();
    int lane = tid & 63, wave = tid >> 6;
    int quad = lane >> 4, l16 = lane & 15;
    int c0 = wave * 16 + l16;        // cols 0..63
    int c1 = 64 + c0;                // cols 64..127
    float4v acc[4][2];
#pragma unroll
    for (int rt = 0; rt < 4; ++rt) {
        float4v z = {0.f, 0.f, 0.f, 0.f};
        acc[rt][0] = z; acc[rt][1] = z;
    }
#pragma unroll
    for (int ks = 0; ks < 4; ++ks) {
        short8 b0 = *(const short8*)(Bt + (size_t)c0 * 128 + ks * 32 + quad * 8);
        short8 b1 = *(const short8*)(Bt + (size_t)c1 * 128 + ks * 32 + quad * 8);
        short8 af[4];
#pragma unroll
        for (int rt = 0; rt < 4; ++rt)
            af[rt] = *(const short8*)(As + (rt * 16 + l16) * 136 + ks * 32 + quad * 8);
#pragma unroll
        for (int rt = 0; rt < 4; ++rt) {
            acc[rt][0] = __builtin_amdgcn_mfma_f32_16x16x32_bf16(af[rt], b0, acc[rt][0], 0, 0, 0);
            acc[rt][1] = __builtin_amdgcn_mfma_f32_16x16x32_bf16(af[rt], b1, acc[rt][1], 0, 0, 0);
        }
    }
    float bc0 = bias[c0], bc1 = bias[c1];
#pragma unroll
    for (int rt = 0; rt < 4; ++rt)
#pragma unroll
        for (int reg = 0; reg < 4; ++reg) {
            int gr = r0 + rt * 16 + quad * 4 + reg;
            if (gr < nrows) {
                float dg = dinv[gr];
                yio[(size_t)gr * 128 + c0] = f2bf(dg * (acc[rt][0][reg] + bc0));
                yio[(size_t)gr * 128 + c1] = f2bf(dg * (acc[rt][1][reg] + bc1));
            }
        }
}

// ---------- GEMM2 + epilogue: [mu|ls] = y2 @ W2t + [bmu|bls]; out = mu + init*exp(ls) ----------
__global__ __launch_bounds__(256) void k_gemm2(
    const unsigned short* __restrict__ y2,   // [NN][128] bf16
    const unsigned short* __restrict__ Bt,   // [128][128] bf16 W2t
    const float* __restrict__ bmu,           // [64] f32
    const float* __restrict__ bls,           // [64] f32
    const float* __restrict__ init,          // [NN][64] f32
    float* __restrict__ outp,                // [NN][64] f32
    int nrows) {
    __shared__ __align__(16) unsigned short As[64 * 136];
    int tid = threadIdx.x;
    int r0 = blockIdx.x * 64;
    for (int c = tid; c < 1024; c += 256) {
        int row = c >> 4, kc = (c & 15) << 3;
        int gr = r0 + row;
        short8 v = {0, 0, 0, 0, 0, 0, 0, 0};
        if (gr < nrows) v = *(const short8*)(y2 + (size_t)gr * 128 + kc);
        *(short8*)(As + row * 136 + kc) = v;
    }
    __syncthreads();
    int lane = tid & 63, wave = tid >> 6;
    int quad = lane >> 4, l16 = lane & 15;
    int cm = wave * 16 + l16;        // mu col (0..63)
    int cl = 64 + cm;                // matching ls col
    float4v acc[4][2];
#pragma unroll
    for (int rt = 0; rt < 4; ++rt) {
        float4v z = {0.f, 0.f, 0.f, 0.f};
        acc[rt][0] = z; acc[rt][1] = z;
    }
#pragma unroll
    for (int ks = 0; ks < 4; ++ks) {
        short8 b0 = *(const short8*)(Bt + (size_t)cm * 128 + ks * 32 + quad * 8);
        short8 b1 = *(const short8*)(Bt + (size_t)cl * 128 + ks * 32 + quad * 8);
        short8 af[4];
#pragma unroll
        for (int rt = 0; rt < 4; ++rt)
            af[rt] = *(const short8*)(As + (rt * 16 + l16) * 136 + ks * 32 + quad * 8);
#pragma unroll
        for (int rt = 0; rt < 4; ++rt) {
            acc[rt][0] = __builtin_amdgcn_mfma_f32_16x16x32_bf16(af[rt], b0, acc[rt][0], 0, 0, 0);
            acc[rt][1] = __builtin_amdgcn_mfma_f32_16x16x32_bf16(af[rt], b1, acc[rt][1], 0, 0, 0);
        }
    }
    float bc_mu = bmu[cm], bc_ls = bls[cm];
#pragma unroll
    for (int rt = 0; rt < 4; ++rt)
#pragma unroll
        for (int reg = 0; reg < 4; ++reg) {
            int gr = r0 + rt * 16 + quad * 4 + reg;
            if (gr < nrows) {
                float mu = acc[rt][0][reg] + bc_mu;
                float ls = acc[rt][1][reg] + bc_ls;
                float idv = init[(size_t)gr * 64 + cm];
                outp[(size_t)gr * 64 + cm] = mu + idv * expf(ls);
            }
        }
}

extern "C" void kernel_launch(void* const* d_in, const int* in_sizes, int n_in,
                              void* d_out, int out_size, void* d_ws, size_t ws_size,
                              hipStream_t stream) {
    const float* x   = (const float*)d_in[0];  // [N,128] f32
    const int*   ei  = (const int*)d_in[1];    // [2,E] int32
    const float* ind = (const float*)d_in[2];  // [N,64] f32
    const float* W1  = (const float*)d_in[3];  // [128,128] f32
    const float* b1  = (const float*)d_in[4];  // [128] f32
    const float* Wmu = (const float*)d_in[5];  // [128,64] f32
    const float* bmu = (const float*)d_in[6];  // [64] f32
    const float* Wls = (const float*)d_in[7];  // [128,64] f32
    const float* bls = (const float*)d_in[8];  // [64] f32
    float* outp = (float*)d_out;               // [N,64] f32

    char* w = (char*)d_ws;
    auto carve = [&](size_t bytes) -> char* {
        char* p = w; w += (bytes + 255) & ~(size_t)255; return p;
    };
    int*   cnt  = (int*)carve((size_t)NN * 4);
    int*   off  = (int*)carve((size_t)(NN + 1) * 4);
    int*   bsum = (int*)carve(128 * 4);
    float* dinv = (float*)carve((size_t)NN * 4);
    int*   csr  = (int*)carve((size_t)NE * 4);
    unsigned short* W1t = (unsigned short*)carve(128 * 128 * 2);
    unsigned short* W2t = (unsigned short*)carve(128 * 128 * 2);
    unsigned short* xs  = (unsigned short*)carve((size_t)NN * 128 * 2);  // rank -> xs -> y2
    unsigned short* y   = (unsigned short*)carve((size_t)NN * 128 * 2);  // y1 -> hs (in-place)
    int* rank = (int*)xs;  // alias: rank (6.4 MB) dead before prescale writes xs
    // total ~59 MB of ws (round-4/5 footprint, proven to fit)

    hipMemsetAsync(cnt, 0, (size_t)NN * 4, stream);
    k_wt<<<128, 256, 0, stream>>>(W1, Wmu, Wls, W1t, W2t);
    k_count_rank<<<(NE / 4 + 255) / 256, 256, 0, stream>>>(ei + NE, cnt, rank);
    k_scanA<<<98, 256, 0, stream>>>(cnt, off, bsum, dinv);
    k_scanB<<<1, 128, 0, stream>>>(bsum, off);
    k_scanC<<<391, 256, 0, stream>>>(off, bsum);
    k_fill2<<<(NE / 4 + 255) / 256, 256, 0, stream>>>(ei, off, rank, csr);
    k_prescale<<<(NN * 32 + 255) / 256, 256, 0, stream>>>(x, dinv, xs);
    k_gather<<<NN / 4, 256, 0, stream>>>(xs, off, csr, dinv, y);            // y1
    k_gemm1<<<(NN + 63) / 64, 256, 0, stream>>>(y, W1t, b1, dinv, NN);      // y -> hs in place
    k_gather<<<NN / 4, 256, 0, stream>>>(y, off, csr, dinv, xs);            // y2 into xs
    k_gemm2<<<(NN + 63) / 64, 256, 0, stream>>>(xs, W2t, bmu, bls, ind, outp, NN);
}